// Round 1
// baseline (1022.870 us; speedup 1.0000x reference)
//
#include <hip/hip_runtime.h>
#include <math.h>

// Problem dims (fixed by reference)
#define N_S 50000
#define C_C 2000
#define D_D 128
#define K_K 8
#define U_U 20000

// ws layout (float offsets)
#define WS_Q      0          // 16000 floats: Q[c*8+k]
#define WS_P      16384      // 1024: UA online-softmax partials [64 blocks][8 k][m,s]
#define WS_MK     17408      // 8: per-k max of UA column
#define WS_ISK    17416      // 8: per-k 1/sumexp of UA column
#define WS_M      17472      // 16000: per-(c,k) max over d of CA
#define WS_IS     33472      // 16000: per-(c,k) 1/sumexp
#define WS_A      49472      // 400000: A[n*8+k]

// ---------------------------------------------------------------------------
// K1a: online column-softmax partials of UA (softmax over U per k), plus zero Q
// grid 64 x 256
__global__ __launch_bounds__(256) void k_ua_part(const float* __restrict__ UA,
                                                 float* __restrict__ ws) {
  int t = threadIdx.x, b = blockIdx.x;
  int gid = b * 256 + t;
  if (gid < C_C * K_K) ws[WS_Q + gid] = 0.f;   // zero Q for atomics
  int k = gid & 7;
  float m = -INFINITY, s = 0.f;
  for (int u = (gid >> 3); u < U_U; u += 2048) {
    float v = UA[u * 8 + k];                    // addr = gid + 16384*i: coalesced
    if (v > m) { s = s * __expf(m - v) + 1.f; m = v; }
    else       { s += __expf(v - m); }
  }
  // merge same-k lanes within wave (k = lane&7): xor offsets 8,16,32
  #pragma unroll
  for (int off = 8; off <= 32; off <<= 1) {
    float om = __shfl_xor(m, off);
    float os = __shfl_xor(s, off);
    float M = fmaxf(m, om);
    s = s * __expf(m - M) + os * __expf(om - M);
    m = M;
  }
  __shared__ float sm[32], ss_[32];             // 4 waves x 8 k
  int l = t & 63, wid = t >> 6;
  if (l < 8) { sm[wid * 8 + l] = m; ss_[wid * 8 + l] = s; }
  __syncthreads();
  if (t < 8) {
    float M = sm[t], S = ss_[t];
    #pragma unroll
    for (int w = 1; w < 4; w++) {
      float om = sm[w * 8 + t], os = ss_[w * 8 + t];
      float MM = fmaxf(M, om);
      S = S * __expf(M - MM) + os * __expf(om - MM);
      M = MM;
    }
    ws[WS_P + b * 16 + t * 2]     = M;
    ws[WS_P + b * 16 + t * 2 + 1] = S;
  }
}

// K1b: final merge of 64 UA partials -> m_k, 1/s_k.  grid 1 x 64
__global__ __launch_bounds__(64) void k_ua_final(float* __restrict__ ws) {
  int t = threadIdx.x;
  if (t >= 8) return;
  float M = -INFINITY, S = 0.f;
  for (int b = 0; b < 64; b++) {
    float om = ws[WS_P + b * 16 + t * 2], os = ws[WS_P + b * 16 + t * 2 + 1];
    float MM = fmaxf(M, om);
    S = S * __expf(M - MM) + os * __expf(om - MM);
    M = MM;
  }
  ws[WS_MK + t]  = M;
  ws[WS_ISK + t] = 1.f / S;
}

// ---------------------------------------------------------------------------
// K3: per-(c,k) softmax stats of CA over d (len 128, stride 8 elems).
// One wave per (c,k). grid 4000 x 256
__global__ __launch_bounds__(256) void k_ca_stats(const float* __restrict__ CA,
                                                  float* __restrict__ ws) {
  int t = threadIdx.x;
  int wid = t >> 6, l = t & 63;
  int p = blockIdx.x * 4 + wid;                 // < 16000
  int c = p >> 3, k = p & 7;
  const float* row = CA + (size_t)c * 1024;
  float v0 = row[l * 8 + k];
  float v1 = row[(l + 64) * 8 + k];
  float m = fmaxf(v0, v1);
  #pragma unroll
  for (int off = 1; off <= 32; off <<= 1) m = fmaxf(m, __shfl_xor(m, off));
  float s = __expf(v0 - m) + __expf(v1 - m);
  #pragma unroll
  for (int off = 1; off <= 32; off <<= 1) s += __shfl_xor(s, off);
  if (l == 0) { ws[WS_M + p] = m; ws[WS_IS + p] = 1.f / s; }
}

// ---------------------------------------------------------------------------
// K4: A[n,k] = (1/s_ck) * sum_d X[n,d]*exp(CA[c,d,k]-m_ck), c=cour[n].
// One wave per sample; lane = (dgroup<<3)|k so CA reads are fully coalesced.
// grid 12500 x 256
__global__ __launch_bounds__(256) void k_act(const float* __restrict__ X,
                                             const int* __restrict__ cour,
                                             const float* __restrict__ CA,
                                             float* __restrict__ ws) {
  int t = threadIdx.x;
  int wid = t >> 6, l = t & 63;
  int n = blockIdx.x * 4 + wid;                 // exactly 50000
  int c = cour[n];
  int k = l & 7, dg = l >> 3;
  float mK  = ws[WS_M + c * 8 + k];
  float isK = ws[WS_IS + c * 8 + k];
  const float* carow = CA + (size_t)c * 1024;
  const float* xrow  = X + (size_t)n * 128;
  float acc = 0.f;
  #pragma unroll
  for (int j = 0; j < 16; j++) {
    float v = carow[l + 64 * j];                // 64 consecutive floats / wave-step
    float x = xrow[dg + 8 * j];
    acc += x * __expf(v - mK);
  }
  acc += __shfl_xor(acc, 8);
  acc += __shfl_xor(acc, 16);
  acc += __shfl_xor(acc, 32);
  if (l < 8) ws[WS_A + n * 8 + l] = acc * isK;  // lane l holds k=l
}

// ---------------------------------------------------------------------------
// K2: fused UC row-softmax + Q accumulation. One block per user (strided).
// Row elements live in per-thread registers (vloc[8]); only (m,S) and the
// 8 UAs values cross threads. Q partials in registers, atomics at the end.
// grid 256 x 256
__global__ __launch_bounds__(256) void k_q(const float* __restrict__ UC,
                                           const float* __restrict__ UA,
                                           float* __restrict__ ws) {
  __shared__ float wm[4], ws4[4], uaS[8];
  int t = threadIdx.x;
  int wid = t >> 6, l = t & 63;
  float rm = 0.f, ris = 0.f;
  if (t < 8) { rm = ws[WS_MK + t]; ris = ws[WS_ISK + t]; }
  float q[8][8];
  #pragma unroll
  for (int j = 0; j < 8; j++)
    #pragma unroll
    for (int k = 0; k < 8; k++) q[j][k] = 0.f;

  for (int u = blockIdx.x; u < U_U; u += gridDim.x) {
    const float* ucrow = UC + (size_t)u * 2000;
    float vloc[8];
    float m = -INFINITY, s = 0.f;
    #pragma unroll
    for (int j = 0; j < 8; j++) {
      int c = t + 256 * j;
      float v = -INFINITY;
      if (c < 2000) v = __builtin_nontemporal_load(ucrow + c);
      vloc[j] = v;
      if (v > m) { s = s * __expf(m - v) + 1.f; m = v; }
      else       { s += __expf(v - m); }       // exp(-inf - m) = 0 for pad lanes
    }
    // full-wave online merge (all lanes same user)
    #pragma unroll
    for (int off = 1; off <= 32; off <<= 1) {
      float om = __shfl_xor(m, off), os = __shfl_xor(s, off);
      float M = fmaxf(m, om);
      s = s * __expf(m - M) + os * __expf(om - M);
      m = M;
    }
    if (l == 0) { wm[wid] = m; ws4[wid] = s; }
    if (t < 8) uaS[t] = __expf(UA[u * 8 + t] - rm) * ris;
    __syncthreads();
    float M = fmaxf(fmaxf(wm[0], wm[1]), fmaxf(wm[2], wm[3]));
    float S = ws4[0] * __expf(wm[0] - M) + ws4[1] * __expf(wm[1] - M) +
              ws4[2] * __expf(wm[2] - M) + ws4[3] * __expf(wm[3] - M);
    float inv = 1.f / S;
    float ua[8];
    #pragma unroll
    for (int k = 0; k < 8; k++) ua[k] = uaS[k];
    #pragma unroll
    for (int j = 0; j < 8; j++) {
      int c = t + 256 * j;
      if (c < 2000) {
        float w = __expf(vloc[j] - M) * inv;
        #pragma unroll
        for (int k = 0; k < 8; k++) q[j][k] += w * ua[k];
      }
    }
    __syncthreads();   // wm/ws4/uaS reused next user
  }
  float* Q = ws + WS_Q;
  #pragma unroll
  for (int j = 0; j < 8; j++) {
    int c = t + 256 * j;
    if (c < 2000) {
      #pragma unroll
      for (int k = 0; k < 8; k++) unsafeAtomicAdd(&Q[c * 8 + k], q[j][k]);
    }
  }
}

// ---------------------------------------------------------------------------
// K5: Y[n,c] = (1 - sig(slide[c]) - sig(guess[c])) * dot8(A[n],Q[c]) + sig(guess[c])
// Block tile: 64 n x 256 c; A tile staged in LDS; nontemporal streaming stores.
// grid (8, 782) x 256
__global__ __launch_bounds__(256) void k_y(const float* __restrict__ guess_,
                                           const float* __restrict__ slide_,
                                           const float* __restrict__ ws,
                                           float* __restrict__ Y) {
  __shared__ float Asm[512];
  int t = threadIdx.x;
  int n0 = blockIdx.y * 64;
  int c = blockIdx.x * 256 + t;
  const float* Aws = ws + WS_A;
  #pragma unroll
  for (int i = 0; i < 2; i++) {
    int idx = t + i * 256;
    int gi = n0 * 8 + idx;
    Asm[idx] = (gi < N_S * 8) ? Aws[gi] : 0.f;
  }
  bool valid = (c < C_C);
  float qv[8] = {0, 0, 0, 0, 0, 0, 0, 0};
  float ac = 0.f, bc = 0.f;
  if (valid) {
    const float* Q = ws + WS_Q;
    #pragma unroll
    for (int k = 0; k < 8; k++) qv[k] = Q[c * 8 + k];
    float sg  = 1.f / (1.f + __expf(-guess_[c]));
    float ssl = 1.f / (1.f + __expf(-slide_[c]));
    ac = 1.f - ssl - sg;
    bc = sg;
  }
  __syncthreads();
  if (!valid) return;
  int nmax = min(64, N_S - n0);
  for (int i = 0; i < nmax; i++) {
    float dot = 0.f;
    #pragma unroll
    for (int k = 0; k < 8; k++) dot += Asm[i * 8 + k] * qv[k];   // LDS broadcast
    float y = fmaf(ac, dot, bc);
    __builtin_nontemporal_store(y, Y + (size_t)(n0 + i) * 2000 + c);
  }
}

// ---------------------------------------------------------------------------
extern "C" void kernel_launch(void* const* d_in, const int* in_sizes, int n_in,
                              void* d_out, int out_size, void* d_ws, size_t ws_size,
                              hipStream_t stream) {
  const float* X      = (const float*)d_in[0];
  const int*   cour   = (const int*)  d_in[1];
  const float* CA     = (const float*)d_in[2];
  const float* UA     = (const float*)d_in[3];
  const float* UC     = (const float*)d_in[4];
  const float* guess_ = (const float*)d_in[5];
  const float* slide_ = (const float*)d_in[6];
  float* Y  = (float*)d_out;
  float* ws = (float*)d_ws;

  hipLaunchKernelGGL(k_ua_part,  dim3(64),      dim3(256), 0, stream, UA, ws);
  hipLaunchKernelGGL(k_ua_final, dim3(1),       dim3(64),  0, stream, ws);
  hipLaunchKernelGGL(k_ca_stats, dim3(4000),    dim3(256), 0, stream, CA, ws);
  hipLaunchKernelGGL(k_act,      dim3(12500),   dim3(256), 0, stream, X, cour, CA, ws);
  hipLaunchKernelGGL(k_q,        dim3(256),     dim3(256), 0, stream, UC, UA, ws);
  hipLaunchKernelGGL(k_y,        dim3(8, 782),  dim3(256), 0, stream, guess_, slide_, ws, Y);
}